// Round 1
// baseline (737.308 us; speedup 1.0000x reference)
//
#include <hip/hip_runtime.h>

#define NA 150381
#define NC 90
#define PK 1024
#define CMAX 4096
#define MDET 100
#define STHR 0.996f
#define NTHR 0.5f
#define IMGF 896.0f

typedef unsigned long long u64;

// ---------------- decode boxes + translation ----------------
__global__ void k_decode(const float* __restrict__ anc, const float* __restrict__ reg,
                         const float* __restrict__ ta, const float* __restrict__ td,
                         float* __restrict__ boxes, float* __restrict__ trn) {
  int i = blockIdx.x * blockDim.x + threadIdx.x;
  if (i >= NA) return;
  float a0 = anc[i*4+0], a1 = anc[i*4+1], a2 = anc[i*4+2], a3 = anc[i*4+3];
  float cxa = (a0 + a2) * 0.5f, cya = (a1 + a3) * 0.5f;
  float wa = a2 - a0, ha = a3 - a1;
  float ty = reg[i*4+0], tx = reg[i*4+1], th = reg[i*4+2], tw = reg[i*4+3];
  float w = expf(tw) * wa, h = expf(th) * ha;
  float cy = ty * ha + cya, cx = tx * wa + cxa;
  float x1 = cx - w * 0.5f, y1 = cy - h * 0.5f;
  float x2 = cx + w * 0.5f, y2 = cy + h * 0.5f;
  x1 = fminf(fmaxf(x1, 0.f), IMGF); y1 = fminf(fmaxf(y1, 0.f), IMGF);
  x2 = fminf(fmaxf(x2, 0.f), IMGF); y2 = fminf(fmaxf(y2, 0.f), IMGF);
  boxes[i*4+0] = x1; boxes[i*4+1] = y1; boxes[i*4+2] = x2; boxes[i*4+3] = y2;
  float st = ta[i*3+2];
  trn[i*3+0] = ta[i*3+0] + td[i*3+0] * st;
  trn[i*3+1] = ta[i*3+1] + td[i*3+1] * st;
  trn[i*3+2] = td[i*3+2];
}

// ---------------- threshold filter into per-class candidate lists ----------------
__global__ void k_collect(const float* __restrict__ cls, int* __restrict__ counts,
                          u64* __restrict__ cand) {
  const int total = NA * NC;
  for (int f = blockIdx.x * blockDim.x + threadIdx.x; f < total; f += gridDim.x * blockDim.x) {
    float v = cls[f];
    if (v > STHR) {
      int c = f % NC;
      int i = f / NC;
      int pos = atomicAdd(&counts[c], 1);
      if (pos < CMAX) {
        // key: score desc, anchor index asc (matches lax.top_k stable tie-break)
        cand[(size_t)c * CMAX + pos] =
            ((u64)__float_as_uint(v) << 32) | (u64)(0xFFFFFFFFu - (unsigned)i);
      }
    }
  }
}

// ---------------- per-class sort (bitonic, descending) -> top-1024 ----------------
__global__ __launch_bounds__(1024) void k_sortclass(const int* __restrict__ counts,
                                                    const u64* __restrict__ cand,
                                                    u64* __restrict__ topk,
                                                    int* __restrict__ mcount) {
  __shared__ u64 buf[CMAX];
  const int c = blockIdx.x, tid = threadIdx.x;
  int M = min(counts[c], CMAX);
  for (int k = tid; k < CMAX; k += blockDim.x)
    buf[k] = (k < M) ? cand[(size_t)c * CMAX + k] : 0ULL;
  for (int k = 2; k <= CMAX; k <<= 1) {
    for (int j = k >> 1; j > 0; j >>= 1) {
      __syncthreads();
      for (int i = tid; i < CMAX; i += blockDim.x) {
        int ixj = i ^ j;
        if (ixj > i) {
          u64 a = buf[i], b = buf[ixj];
          if (((i & k) == 0) ? (a < b) : (a > b)) { buf[i] = b; buf[ixj] = a; }
        }
      }
    }
  }
  __syncthreads();
  for (int k = tid; k < PK; k += blockDim.x) topk[(size_t)c * PK + k] = buf[k];
  if (tid == 0) mcount[c] = min(M, PK);
}

// ---------------- per-class greedy NMS (sequential over sorted order) ----------------
__global__ __launch_bounds__(256) void k_nms(const u64* __restrict__ topk,
                                             const int* __restrict__ mcount,
                                             const float* __restrict__ boxes,
                                             unsigned* __restrict__ keep_out) {
  __shared__ float bx1[PK], by1[PK], bx2[PK], by2[PK], ar[PK];
  __shared__ unsigned keep[PK / 32];
  const int c = blockIdx.x, tid = threadIdx.x;
  const int M = mcount[c];
  for (int t = tid; t < M; t += blockDim.x) {
    u64 key = topk[(size_t)c * PK + t];
    unsigned aidx = 0xFFFFFFFFu - (unsigned)(key & 0xFFFFFFFFull);
    float x1 = boxes[aidx*4+0], y1 = boxes[aidx*4+1];
    float x2 = boxes[aidx*4+2], y2 = boxes[aidx*4+3];
    bx1[t] = x1; by1[t] = y1; bx2[t] = x2; by2[t] = y2;
    ar[t] = (x2 - x1) * (y2 - y1);
  }
  for (int t = tid; t < PK / 32; t += blockDim.x) {
    int lo = t * 32;
    unsigned m = 0xFFFFFFFFu;
    if (M <= lo) m = 0u;
    else if (M - lo < 32) m = (1u << (M - lo)) - 1u;
    keep[t] = m;
  }
  __syncthreads();
  for (int i = 0; i < M; ++i) {
    bool ki = (keep[i >> 5] >> (i & 31)) & 1u;
    if (ki) {
      float x1 = bx1[i], y1 = by1[i], x2 = bx2[i], y2 = by2[i], ai = ar[i];
      for (int j = i + 1 + tid; j < M; j += blockDim.x) {
        float ix1 = fmaxf(x1, bx1[j]), iy1 = fmaxf(y1, by1[j]);
        float ix2 = fminf(x2, bx2[j]), iy2 = fminf(y2, by2[j]);
        float iw = fmaxf(ix2 - ix1, 0.f), ih = fmaxf(iy2 - iy1, 0.f);
        float inter = iw * ih;
        float uni = ai + ar[j] - inter;
        float iou = inter / fmaxf(uni, 1e-9f);
        if (iou > NTHR) atomicAnd(&keep[j >> 5], ~(1u << (j & 31)));
      }
    }
    __syncthreads();
  }
  for (int t = tid; t < PK / 32; t += blockDim.x)
    keep_out[c * (PK / 32) + t] = keep[t];
}

// ---------------- global top-100 + gather ----------------
__global__ __launch_bounds__(1024) void k_final(const u64* __restrict__ topk,
                                                const unsigned* __restrict__ keep,
                                                const float* __restrict__ boxes,
                                                const float* __restrict__ rot,
                                                const float* __restrict__ trn,
                                                float* __restrict__ out) {
  extern __shared__ u64 buf[];  // 16384 slots = 128 KB
  const int NS = 16384;
  const int tid = threadIdx.x;
  for (int k = tid; k < NS; k += blockDim.x) buf[k] = 0ULL;
  __syncthreads();

  // Collect first <=100 kept per class (positions ascending == scores descending)
  const int wave = tid >> 6;
  const int lane = tid & 63;
  for (int c = wave; c < NC; c += 16) {
    if (lane < 32) {
      unsigned w = keep[c * 32 + lane];
      int pc = __popc(w);
      int scan = pc;
      for (int d = 1; d < 32; d <<= 1) {
        int v = __shfl_up(scan, d);
        if (lane >= d) scan += v;
      }
      int base = scan - pc;  // exclusive prefix of kept count
      unsigned ww = w;
      while (ww) {
        int b = __ffs(ww) - 1;
        ww &= ww - 1u;
        if (base < MDET) {
          int pos = lane * 32 + b;
          u64 tkey = topk[(size_t)c * PK + pos];
          unsigned flat = (unsigned)(c * PK + pos);
          // key: score desc, flat index asc (matches top_k over flattened array)
          buf[c * MDET + base] =
              (tkey & 0xFFFFFFFF00000000ull) | (u64)(0xFFFFFFFFu - flat);
        }
        base++;
      }
    }
  }
  __syncthreads();

  // Bitonic sort descending over 16384
  for (int k = 2; k <= NS; k <<= 1) {
    for (int j = k >> 1; j > 0; j >>= 1) {
      for (int i = tid; i < NS; i += blockDim.x) {
        int ixj = i ^ j;
        if (ixj > i) {
          u64 a = buf[i], b = buf[ixj];
          if (((i & k) == 0) ? (a < b) : (a > b)) { buf[i] = b; buf[ixj] = a; }
        }
      }
      __syncthreads();
    }
  }

  // Gather top-100 outputs
  if (tid < MDET) {
    u64 key = buf[tid];
    bool ok = (key != 0ULL);
    float b0 = -1.f, b1 = -1.f, b2 = -1.f, b3 = -1.f;
    float r0 = -1.f, r1 = -1.f, r2 = -1.f;
    float t0 = -1.f, t1 = -1.f, t2 = -1.f;
    float sc = -1.f, lab = -1.f;
    if (ok) {
      float score = __uint_as_float((unsigned)(key >> 32));
      unsigned flat = 0xFFFFFFFFu - (unsigned)(key & 0xFFFFFFFFull);
      int c = flat >> 10, pos = flat & 1023;
      u64 tkey = topk[(size_t)c * PK + pos];
      unsigned aidx = 0xFFFFFFFFu - (unsigned)(tkey & 0xFFFFFFFFull);
      b0 = boxes[aidx*4+0]; b1 = boxes[aidx*4+1];
      b2 = boxes[aidx*4+2]; b3 = boxes[aidx*4+3];
      sc = score; lab = (float)c;
      r0 = rot[aidx*3+0]; r1 = rot[aidx*3+1]; r2 = rot[aidx*3+2];
      t0 = trn[aidx*3+0]; t1 = trn[aidx*3+1]; t2 = trn[aidx*3+2];
    }
    out[tid*4+0] = b0; out[tid*4+1] = b1; out[tid*4+2] = b2; out[tid*4+3] = b3;
    out[400 + tid] = sc;
    out[500 + tid] = lab;
    out[600 + tid*3+0] = r0; out[600 + tid*3+1] = r1; out[600 + tid*3+2] = r2;
    out[900 + tid*3+0] = t0; out[900 + tid*3+1] = t1; out[900 + tid*3+2] = t2;
  }
}

extern "C" void kernel_launch(void* const* d_in, const int* in_sizes, int n_in,
                              void* d_out, int out_size, void* d_ws, size_t ws_size,
                              hipStream_t stream) {
  const float* anchors        = (const float*)d_in[0];
  const float* regression     = (const float*)d_in[1];
  const float* classification = (const float*)d_in[2];
  const float* rotation       = (const float*)d_in[3];
  const float* tanch          = (const float*)d_in[4];
  const float* tdelta         = (const float*)d_in[5];
  float* out = (float*)d_out;

  char* ws = (char*)d_ws;
  size_t off = 0;
  auto alloc = [&](size_t bytes) -> void* {
    void* p = ws + off;
    off += (bytes + 255) & ~(size_t)255;
    return p;
  };
  float*    boxes  = (float*)alloc((size_t)NA * 4 * 4);
  float*    trn    = (float*)alloc((size_t)NA * 3 * 4);
  int*      counts = (int*)alloc(NC * 4);
  int*      mcount = (int*)alloc(NC * 4);
  u64*      cand   = (u64*)alloc((size_t)NC * CMAX * 8);
  u64*      topk   = (u64*)alloc((size_t)NC * PK * 8);
  unsigned* keep   = (unsigned*)alloc(NC * 32 * 4);

  hipMemsetAsync(counts, 0, NC * 4, stream);

  k_decode<<<(NA + 255) / 256, 256, 0, stream>>>(anchors, regression, tanch, tdelta, boxes, trn);
  k_collect<<<2048, 256, 0, stream>>>(classification, counts, cand);
  k_sortclass<<<NC, 1024, 0, stream>>>(counts, cand, topk, mcount);
  k_nms<<<NC, 256, 0, stream>>>(topk, mcount, boxes, keep);

  // allow 128 KB dynamic LDS for the final sort (no-op if already allowed)
  hipFuncSetAttribute(reinterpret_cast<const void*>(k_final),
                      hipFuncAttributeMaxDynamicSharedMemorySize, 131072);
  k_final<<<1, 1024, 131072, stream>>>(topk, keep, boxes, rotation, trn, out);
}